// Round 1
// baseline (596.199 us; speedup 1.0000x reference)
//
#include <hip/hip_runtime.h>
#include <hip/hip_bf16.h>

#define N_NODES 10000
#define S_NB 20
#define D_IN 512
#define D_OUT 512
#define ATTEN_D 64
#define KTOT 1024            // 2*D_IN (stacked self|neigh)
#define M_PAD 10048          // 157 * 64

typedef __bf16 bf16_t;
typedef bf16_t bf16x8 __attribute__((ext_vector_type(8)));
typedef float f32x4 __attribute__((ext_vector_type(4)));

__device__ __forceinline__ unsigned short f2bf(float f) {
    unsigned int u = __float_as_uint(f);
    unsigned int r = u + 0x7FFFu + ((u >> 16) & 1u);   // RNE
    return (unsigned short)(r >> 16);
}

__device__ __forceinline__ void gl_lds16(const unsigned short* g, unsigned short* l) {
    __builtin_amdgcn_global_load_lds(
        (const __attribute__((address_space(1))) void*)g,
        (__attribute__((address_space(3))) void*)l,
        16, 0, 0);
}

// ---------------------------------------------------------------------------
// Kernel 0: precompute u_self = self_atten @ v, u_neigh = neigh_atten @ v,
// cast+transpose stacked weights into Wt[n][k] (bf16), zero X pad rows.
// ---------------------------------------------------------------------------
__global__ void prep_kernel(const float* __restrict__ neigh_w,
                            const float* __restrict__ self_w,
                            const float* __restrict__ self_atten,
                            const float* __restrict__ neigh_atten,
                            const float* __restrict__ v,
                            float* __restrict__ u_self, float* __restrict__ u_neigh,
                            unsigned short* __restrict__ Wt,
                            unsigned short* __restrict__ X) {
    int idx = blockIdx.x * blockDim.x + threadIdx.x;
    int stride = gridDim.x * blockDim.x;

    // Wt[n][k] = (k < 512 ? self_w[k][n] : neigh_w[k-512][n]) as bf16
    for (int i = idx; i < D_OUT * KTOT; i += stride) {
        int n = i >> 10;
        int k = i & (KTOT - 1);
        float w = (k < D_IN) ? self_w[k * D_OUT + n] : neigh_w[(k - D_IN) * D_OUT + n];
        Wt[i] = f2bf(w);
    }
    // u vectors (1024 dot products of length 64)
    for (int i = idx; i < 2 * D_IN; i += stride) {
        const float* row = (i < D_IN) ? (self_atten + (size_t)i * ATTEN_D)
                                      : (neigh_atten + (size_t)(i - D_IN) * ATTEN_D);
        float s = 0.f;
        #pragma unroll
        for (int j = 0; j < ATTEN_D; ++j) s = fmaf(row[j], v[j], s);
        if (i < D_IN) u_self[i] = s; else u_neigh[i - D_IN] = s;
    }
    // zero pad rows of X (rows N_NODES..M_PAD-1)
    for (int i = idx; i < (M_PAD - N_NODES) * KTOT; i += stride) {
        X[(size_t)N_NODES * KTOT + i] = 0;
    }
}

// ---------------------------------------------------------------------------
// Kernel 1: per-node aggregation + gate computation + bf16 X row write.
// One 128-thread block per node; thread t owns float4 columns [4t, 4t+3].
// ---------------------------------------------------------------------------
__global__ __launch_bounds__(128) void aggregate_kernel(
        const float* __restrict__ self_vecs, const float* __restrict__ neigh_vecs,
        const float* __restrict__ neigh_weight, const int* __restrict__ neigh_column,
        const float* __restrict__ alpha,
        const float* __restrict__ u_self, const float* __restrict__ u_neigh,
        unsigned short* __restrict__ X) {
    const int n = blockIdx.x;
    const int tid = threadIdx.x;

    __shared__ float coef[S_NB];
    __shared__ float ew[2 * S_NB];
    __shared__ float red[4];
    __shared__ float gates[2];

    if (tid < S_NB) {
        int col = neigh_column[n * S_NB + tid];
        ew[tid] = expf(alpha[col]);
        ew[S_NB + tid] = neigh_weight[n * S_NB + tid];
    }
    __syncthreads();
    if (tid == 0) {
        float s = 0.f;
        for (int i = 0; i < S_NB; ++i) s += ew[i];
        float inv = 1.0f / s;
        for (int i = 0; i < S_NB; ++i) coef[i] = ew[S_NB + i] * ew[i] * inv;
    }
    __syncthreads();

    const float4* nb = (const float4*)(neigh_vecs + (size_t)n * S_NB * D_IN);
    float4 acc = make_float4(0.f, 0.f, 0.f, 0.f);
    #pragma unroll
    for (int s = 0; s < S_NB; ++s) {
        float4 t = nb[s * 128 + tid];
        float c = coef[s];
        acc.x = fmaf(c, t.x, acc.x);
        acc.y = fmaf(c, t.y, acc.y);
        acc.z = fmaf(c, t.z, acc.z);
        acc.w = fmaf(c, t.w, acc.w);
    }
    float4 sv = ((const float4*)(self_vecs + (size_t)n * D_IN))[tid];
    float4 us = ((const float4*)u_self)[tid];
    float4 un = ((const float4*)u_neigh)[tid];
    float p1 = sv.x * us.x + sv.y * us.y + sv.z * us.z + sv.w * us.w;
    float p2 = acc.x * un.x + acc.y * un.y + acc.z * un.z + acc.w * un.w;

    #pragma unroll
    for (int off = 32; off > 0; off >>= 1) {
        p1 += __shfl_down(p1, off, 64);
        p2 += __shfl_down(p2, off, 64);
    }
    int lane = tid & 63, wid = tid >> 6;
    if (lane == 0) { red[wid * 2] = p1; red[wid * 2 + 1] = p2; }
    __syncthreads();
    if (tid == 0) {
        float s1 = red[0] + red[2];   // self_vecs . u_self
        float s2 = red[1] + red[3];   // neigh_sum . u_neigh
        float a_s = expf(tanhf(2.0f * s1));
        float a_n = expf(tanhf(s2 + s1));
        float inv = 1.0f / (a_s + a_n);
        gates[0] = a_s * inv;
        gates[1] = a_n * inv;
    }
    __syncthreads();
    float gs = gates[0], gn = gates[1];

    unsigned short* xrow = X + (size_t)n * KTOT;
    ushort4 o;
    o.x = f2bf(gs * sv.x); o.y = f2bf(gs * sv.y);
    o.z = f2bf(gs * sv.z); o.w = f2bf(gs * sv.w);
    *(ushort4*)(xrow + tid * 4) = o;
    o.x = f2bf(gn * acc.x); o.y = f2bf(gn * acc.y);
    o.z = f2bf(gn * acc.z); o.w = f2bf(gn * acc.w);
    *(ushort4*)(xrow + D_IN + tid * 4) = o;
}

// ---------------------------------------------------------------------------
// Kernel 2: out = relu(X[M,1024] @ W[1024,512]) using bf16 MFMA.
// BM=64, BN=128, BK=32; 256 threads = 4 waves in 2x2 grid; each wave 32x64.
// ---------------------------------------------------------------------------
#define BM 64
#define BN 128
#define BK 32

__global__ __launch_bounds__(256) void gemm_kernel(
        const unsigned short* __restrict__ X, const unsigned short* __restrict__ Wt,
        float* __restrict__ out) {
    __shared__ __align__(16) unsigned short As[BM * BK];   // [64][32]
    __shared__ __align__(16) unsigned short Bs[BN * BK];   // [128][32] rows = out cols
    const int tid = threadIdx.x;
    const int lane = tid & 63;
    const int wid = tid >> 6;
    const int m0 = blockIdx.y * BM;
    const int n0 = blockIdx.x * BN;
    const int wm = (wid >> 1) * 32;
    const int wn = (wid & 1) * 64;
    const int quad = lane >> 4;
    const int mrow = lane & 15;

    f32x4 acc[2][4];
    f32x4 zero = {0.f, 0.f, 0.f, 0.f};
    #pragma unroll
    for (int i = 0; i < 2; ++i)
        #pragma unroll
        for (int j = 0; j < 4; ++j) acc[i][j] = zero;

    // staging addresses: each wave stages its contiguous LDS quarter (A) /
    // half-row-block (B) as base + lane*16B (global_load_lds placement rule)
    const int lr = lane >> 2;          // 0..15
    const int lk = (lane & 3) * 8;     // bf16 element offset within BK
    const unsigned short* gA  = X  + (size_t)(m0 + wid * 16 + lr) * KTOT + lk;
    const unsigned short* gB0 = Wt + (size_t)(n0 + wid * 32 + lr) * KTOT + lk;
    const unsigned short* gB1 = Wt + (size_t)(n0 + wid * 32 + 16 + lr) * KTOT + lk;
    unsigned short* lA  = As + wid * 512 + lane * 8;
    unsigned short* lB0 = Bs + wid * 1024 + lane * 8;
    unsigned short* lB1 = Bs + wid * 1024 + 512 + lane * 8;

    for (int k0 = 0; k0 < KTOT; k0 += BK) {
        __syncthreads();               // LDS safe to overwrite
        gl_lds16(gA + k0, lA);
        gl_lds16(gB0 + k0, lB0);
        gl_lds16(gB1 + k0, lB1);
        __syncthreads();               // staged data visible

        bf16x8 a[2], b[4];
        #pragma unroll
        for (int i = 0; i < 2; ++i)
            a[i] = *(const bf16x8*)(As + (wm + i * 16 + mrow) * BK + quad * 8);
        #pragma unroll
        for (int j = 0; j < 4; ++j)
            b[j] = *(const bf16x8*)(Bs + (wn + j * 16 + mrow) * BK + quad * 8);
        #pragma unroll
        for (int i = 0; i < 2; ++i)
            #pragma unroll
            for (int j = 0; j < 4; ++j)
                acc[i][j] = __builtin_amdgcn_mfma_f32_16x16x32_bf16(a[i], b[j], acc[i][j], 0, 0, 0);
    }

    // epilogue: C/D layout col=lane&15, row=quad*4+reg
    #pragma unroll
    for (int i = 0; i < 2; ++i) {
        int rbase = m0 + wm + i * 16 + quad * 4;
        #pragma unroll
        for (int j = 0; j < 4; ++j) {
            int c = n0 + wn + j * 16 + mrow;
            #pragma unroll
            for (int r = 0; r < 4; ++r) {
                int R = rbase + r;
                if (R < N_NODES)
                    out[(size_t)R * D_OUT + c] = fmaxf(acc[i][j][r], 0.f);
            }
        }
    }
}

extern "C" void kernel_launch(void* const* d_in, const int* in_sizes, int n_in,
                              void* d_out, int out_size, void* d_ws, size_t ws_size,
                              hipStream_t stream) {
    const float* self_vecs     = (const float*)d_in[0];
    const float* neigh_vecs    = (const float*)d_in[1];
    const float* neigh_weight  = (const float*)d_in[2];
    const int*   neigh_column  = (const int*)d_in[3];
    const float* neigh_weights = (const float*)d_in[4];
    const float* self_weights  = (const float*)d_in[5];
    const float* alpha         = (const float*)d_in[6];
    const float* self_atten    = (const float*)d_in[7];
    const float* neigh_atten   = (const float*)d_in[8];
    const float* v             = (const float*)d_in[9];
    float* out = (float*)d_out;

    char* ws = (char*)d_ws;
    float* u_self  = (float*)ws;                                   // 512 f32
    float* u_neigh = u_self + D_IN;                                // 512 f32
    unsigned short* Wt = (unsigned short*)(ws + 4096);             // 512*1024 bf16 = 1 MB
    unsigned short* X  = (unsigned short*)(ws + 4096 + (size_t)D_OUT * KTOT * 2); // M_PAD*1024 bf16

    hipLaunchKernelGGL(prep_kernel, dim3(256), dim3(256), 0, stream,
                       neigh_weights, self_weights, self_atten, neigh_atten, v,
                       u_self, u_neigh, Wt, X);
    hipLaunchKernelGGL(aggregate_kernel, dim3(N_NODES), dim3(128), 0, stream,
                       self_vecs, neigh_vecs, neigh_weight, neigh_column, alpha,
                       u_self, u_neigh, X);
    hipLaunchKernelGGL(gemm_kernel, dim3(D_OUT / BN, M_PAD / BM), dim3(256), 0, stream,
                       X, Wt, out);
}

// Round 2
// 595.503 us; speedup vs baseline: 1.0012x; 1.0012x over previous
//
#include <hip/hip_runtime.h>
#include <hip/hip_bf16.h>

#define N_NODES 10000
#define S_NB 20
#define D_IN 512
#define D_OUT 512
#define ATTEN_D 64
#define KTOT 1024            // 2*D_IN (stacked self|neigh)
#define M_PAD 10048          // 157 * 64

typedef __bf16 bf16_t;
typedef bf16_t bf16x8 __attribute__((ext_vector_type(8)));
typedef float f32x4 __attribute__((ext_vector_type(4)));

__device__ __forceinline__ unsigned short f2bf(float f) {
    unsigned int u = __float_as_uint(f);
    unsigned int r = u + 0x7FFFu + ((u >> 16) & 1u);   // RNE
    return (unsigned short)(r >> 16);
}

__device__ __forceinline__ void gl_lds16(const unsigned short* g, unsigned short* l) {
    __builtin_amdgcn_global_load_lds(
        (const __attribute__((address_space(1))) void*)g,
        (__attribute__((address_space(3))) void*)l,
        16, 0, 0);
}

// ---------------------------------------------------------------------------
// Kernel 0: precompute u_self = self_atten @ v, u_neigh = neigh_atten @ v,
// cast+transpose stacked weights into Wt[n][k] (bf16), zero X pad rows.
// ---------------------------------------------------------------------------
__global__ void prep_kernel(const float* __restrict__ neigh_w,
                            const float* __restrict__ self_w,
                            const float* __restrict__ self_atten,
                            const float* __restrict__ neigh_atten,
                            const float* __restrict__ v,
                            float* __restrict__ u_self, float* __restrict__ u_neigh,
                            unsigned short* __restrict__ Wt,
                            unsigned short* __restrict__ X) {
    int idx = blockIdx.x * blockDim.x + threadIdx.x;
    int stride = gridDim.x * blockDim.x;

    // Wt[n][k] = (k < 512 ? self_w[k][n] : neigh_w[k-512][n]) as bf16
    // (reads strided but the 2 MB source is L2-resident after first touch)
    for (int i = idx; i < D_OUT * KTOT; i += stride) {
        int n = i >> 10;
        int k = i & (KTOT - 1);
        float w = (k < D_IN) ? self_w[k * D_OUT + n] : neigh_w[(k - D_IN) * D_OUT + n];
        Wt[i] = f2bf(w);
    }
    // u vectors (1024 dot products of length 64)
    for (int i = idx; i < 2 * D_IN; i += stride) {
        const float* row = (i < D_IN) ? (self_atten + (size_t)i * ATTEN_D)
                                      : (neigh_atten + (size_t)(i - D_IN) * ATTEN_D);
        float s = 0.f;
        #pragma unroll
        for (int j = 0; j < ATTEN_D; ++j) s = fmaf(row[j], v[j], s);
        if (i < D_IN) u_self[i] = s; else u_neigh[i - D_IN] = s;
    }
    // zero pad rows of X (rows N_NODES..M_PAD-1); ws is re-poisoned each call
    for (int i = idx; i < (M_PAD - N_NODES) * KTOT; i += stride) {
        X[(size_t)N_NODES * KTOT + i] = 0;
    }
}

// ---------------------------------------------------------------------------
// Kernel 1: per-node aggregation + gate computation + bf16 X row write.
// One 128-thread block per node; thread t owns float4 columns [4t, 4t+3].
// ---------------------------------------------------------------------------
__global__ __launch_bounds__(128) void aggregate_kernel(
        const float* __restrict__ self_vecs, const float* __restrict__ neigh_vecs,
        const float* __restrict__ neigh_weight, const int* __restrict__ neigh_column,
        const float* __restrict__ alpha,
        const float* __restrict__ u_self, const float* __restrict__ u_neigh,
        unsigned short* __restrict__ X) {
    const int n = blockIdx.x;
    const int tid = threadIdx.x;

    __shared__ float coef[S_NB];
    __shared__ float red[4];
    __shared__ float gates[2];

    // parallel softmax over the 20 neighbors (wave 0 only; serial loop removed)
    if (tid < 64) {
        float e = 0.f, wgt = 0.f;
        if (tid < S_NB) {
            e = expf(alpha[neigh_column[n * S_NB + tid]]);
            wgt = neigh_weight[n * S_NB + tid];
        }
        float s = e;
        #pragma unroll
        for (int off = 32; off > 0; off >>= 1) s += __shfl_down(s, off, 64);
        s = __shfl(s, 0, 64);
        if (tid < S_NB) coef[tid] = wgt * e / s;
    }
    __syncthreads();

    const float4* nb = (const float4*)(neigh_vecs + (size_t)n * S_NB * D_IN);
    float4 acc = make_float4(0.f, 0.f, 0.f, 0.f);
    #pragma unroll
    for (int s = 0; s < S_NB; ++s) {
        float4 t = nb[s * 128 + tid];
        float c = coef[s];
        acc.x = fmaf(c, t.x, acc.x);
        acc.y = fmaf(c, t.y, acc.y);
        acc.z = fmaf(c, t.z, acc.z);
        acc.w = fmaf(c, t.w, acc.w);
    }
    float4 sv = ((const float4*)(self_vecs + (size_t)n * D_IN))[tid];
    float4 us = ((const float4*)u_self)[tid];
    float4 un = ((const float4*)u_neigh)[tid];
    float p1 = sv.x * us.x + sv.y * us.y + sv.z * us.z + sv.w * us.w;
    float p2 = acc.x * un.x + acc.y * un.y + acc.z * un.z + acc.w * un.w;

    #pragma unroll
    for (int off = 32; off > 0; off >>= 1) {
        p1 += __shfl_down(p1, off, 64);
        p2 += __shfl_down(p2, off, 64);
    }
    int lane = tid & 63, wid = tid >> 6;
    if (lane == 0) { red[wid * 2] = p1; red[wid * 2 + 1] = p2; }
    __syncthreads();
    if (tid == 0) {
        float s1 = red[0] + red[2];   // self_vecs . u_self
        float s2 = red[1] + red[3];   // neigh_sum . u_neigh
        float a_s = expf(tanhf(2.0f * s1));
        float a_n = expf(tanhf(s2 + s1));
        float inv = 1.0f / (a_s + a_n);
        gates[0] = a_s * inv;
        gates[1] = a_n * inv;
    }
    __syncthreads();
    float gs = gates[0], gn = gates[1];

    unsigned short* xrow = X + (size_t)n * KTOT;
    ushort4 o;
    o.x = f2bf(gs * sv.x); o.y = f2bf(gs * sv.y);
    o.z = f2bf(gs * sv.z); o.w = f2bf(gs * sv.w);
    *(ushort4*)(xrow + tid * 4) = o;
    o.x = f2bf(gn * acc.x); o.y = f2bf(gn * acc.y);
    o.z = f2bf(gn * acc.z); o.w = f2bf(gn * acc.w);
    *(ushort4*)(xrow + D_IN + tid * 4) = o;
}

// ---------------------------------------------------------------------------
// Kernel 2: out = relu(X[M,1024] @ W[1024,512]) using bf16 MFMA.
// BM=64, BN=128, BK=64; 256 threads = 4 waves in 2x2 grid; each wave 32x64.
// BK=64 halves the barrier/vmcnt-drain count vs BK=32 (16 K-iters).
// ---------------------------------------------------------------------------
#define BM 64
#define BN 128
#define BK 64

__global__ __launch_bounds__(256) void gemm_kernel(
        const unsigned short* __restrict__ X, const unsigned short* __restrict__ Wt,
        float* __restrict__ out) {
    __shared__ __align__(16) unsigned short As[BM * BK];   // [64][64]  8 KB
    __shared__ __align__(16) unsigned short Bs[BN * BK];   // [128][64] 16 KB, rows = out cols
    const int tid = threadIdx.x;
    const int lane = tid & 63;
    const int wid = tid >> 6;
    const int m0 = blockIdx.y * BM;
    const int n0 = blockIdx.x * BN;
    const int wm = (wid >> 1) * 32;
    const int wn = (wid & 1) * 64;
    const int quad = lane >> 4;
    const int mrow = lane & 15;

    f32x4 acc[2][4];
    f32x4 zero = {0.f, 0.f, 0.f, 0.f};
    #pragma unroll
    for (int i = 0; i < 2; ++i)
        #pragma unroll
        for (int j = 0; j < 4; ++j) acc[i][j] = zero;

    // staging: thread t loads 16B at row (chunk*32 + t/8), kpos (t%8)*8.
    // LDS dest = chunk_base + t*8 elements = wave-uniform base + lane*16B. OK.
    const int srow = tid >> 3;          // 0..31
    const int skp  = (tid & 7) * 8;     // bf16 k offset within BK
    const unsigned short* gA0 = X  + (size_t)(m0 + srow) * KTOT + skp;
    const unsigned short* gA1 = X  + (size_t)(m0 + 32 + srow) * KTOT + skp;
    const unsigned short* gB0 = Wt + (size_t)(n0 + srow) * KTOT + skp;
    const unsigned short* gB1 = Wt + (size_t)(n0 + 32 + srow) * KTOT + skp;
    const unsigned short* gB2 = Wt + (size_t)(n0 + 64 + srow) * KTOT + skp;
    const unsigned short* gB3 = Wt + (size_t)(n0 + 96 + srow) * KTOT + skp;
    unsigned short* lA0 = As + tid * 8;
    unsigned short* lA1 = As + 2048 + tid * 8;
    unsigned short* lB0 = Bs + tid * 8;
    unsigned short* lB1 = Bs + 2048 + tid * 8;
    unsigned short* lB2 = Bs + 4096 + tid * 8;
    unsigned short* lB3 = Bs + 6144 + tid * 8;

    for (int k0 = 0; k0 < KTOT; k0 += BK) {
        __syncthreads();               // LDS safe to overwrite
        gl_lds16(gA0 + k0, lA0);
        gl_lds16(gA1 + k0, lA1);
        gl_lds16(gB0 + k0, lB0);
        gl_lds16(gB1 + k0, lB1);
        gl_lds16(gB2 + k0, lB2);
        gl_lds16(gB3 + k0, lB3);
        __syncthreads();               // staged data visible

        #pragma unroll
        for (int s = 0; s < 2; ++s) {
            bf16x8 a[2], b[4];
            #pragma unroll
            for (int i = 0; i < 2; ++i)
                a[i] = *(const bf16x8*)(As + (wm + i * 16 + mrow) * BK + s * 32 + quad * 8);
            #pragma unroll
            for (int j = 0; j < 4; ++j)
                b[j] = *(const bf16x8*)(Bs + (wn + j * 16 + mrow) * BK + s * 32 + quad * 8);
            #pragma unroll
            for (int i = 0; i < 2; ++i)
                #pragma unroll
                for (int j = 0; j < 4; ++j)
                    acc[i][j] = __builtin_amdgcn_mfma_f32_16x16x32_bf16(a[i], b[j], acc[i][j], 0, 0, 0);
        }
    }

    // epilogue: C/D layout col=lane&15, row=quad*4+reg
    #pragma unroll
    for (int i = 0; i < 2; ++i) {
        int rbase = m0 + wm + i * 16 + quad * 4;
        #pragma unroll
        for (int j = 0; j < 4; ++j) {
            int c = n0 + wn + j * 16 + mrow;
            #pragma unroll
            for (int r = 0; r < 4; ++r) {
                int R = rbase + r;
                if (R < N_NODES)
                    out[(size_t)R * D_OUT + c] = fmaxf(acc[i][j][r], 0.f);
            }
        }
    }
}

extern "C" void kernel_launch(void* const* d_in, const int* in_sizes, int n_in,
                              void* d_out, int out_size, void* d_ws, size_t ws_size,
                              hipStream_t stream) {
    const float* self_vecs     = (const float*)d_in[0];
    const float* neigh_vecs    = (const float*)d_in[1];
    const float* neigh_weight  = (const float*)d_in[2];
    const int*   neigh_column  = (const int*)d_in[3];
    const float* neigh_weights = (const float*)d_in[4];
    const float* self_weights  = (const float*)d_in[5];
    const float* alpha         = (const float*)d_in[6];
    const float* self_atten    = (const float*)d_in[7];
    const float* neigh_atten   = (const float*)d_in[8];
    const float* v             = (const float*)d_in[9];
    float* out = (float*)d_out;

    char* ws = (char*)d_ws;
    float* u_self  = (float*)ws;                                   // 512 f32
    float* u_neigh = u_self + D_IN;                                // 512 f32
    unsigned short* Wt = (unsigned short*)(ws + 4096);             // 512*1024 bf16 = 1 MB
    unsigned short* X  = (unsigned short*)(ws + 4096 + (size_t)D_OUT * KTOT * 2); // M_PAD*1024 bf16

    hipLaunchKernelGGL(prep_kernel, dim3(1024), dim3(256), 0, stream,
                       neigh_weights, self_weights, self_atten, neigh_atten, v,
                       u_self, u_neigh, Wt, X);
    hipLaunchKernelGGL(aggregate_kernel, dim3(N_NODES), dim3(128), 0, stream,
                       self_vecs, neigh_vecs, neigh_weight, neigh_column, alpha,
                       u_self, u_neigh, X);
    hipLaunchKernelGGL(gemm_kernel, dim3(D_OUT / BN, M_PAD / BM), dim3(256), 0, stream,
                       X, Wt, out);
}

// Round 3
// 594.187 us; speedup vs baseline: 1.0034x; 1.0022x over previous
//
#include <hip/hip_runtime.h>
#include <hip/hip_bf16.h>

#define N_NODES 10000
#define S_NB 20
#define D_IN 512
#define D_OUT 512
#define ATTEN_D 64
#define KTOT 1024            // 2*D_IN (stacked self|neigh)
#define M_PAD 10048          // 157 * 64

typedef __bf16 bf16_t;
typedef bf16_t bf16x8 __attribute__((ext_vector_type(8)));
typedef float f32x4 __attribute__((ext_vector_type(4)));
typedef unsigned short u16x8 __attribute__((ext_vector_type(8)));

__device__ __forceinline__ unsigned short f2bf(float f) {
    unsigned int u = __float_as_uint(f);
    unsigned int r = u + 0x7FFFu + ((u >> 16) & 1u);   // RNE
    return (unsigned short)(r >> 16);
}

__device__ __forceinline__ void gl_lds16(const unsigned short* g, unsigned short* l) {
    __builtin_amdgcn_global_load_lds(
        (const __attribute__((address_space(1))) void*)g,
        (__attribute__((address_space(3))) void*)l,
        16, 0, 0);
}

// ---------------------------------------------------------------------------
// Kernel 0: precompute u_self = self_atten @ v, u_neigh = neigh_atten @ v,
// cast+transpose stacked weights into Wt[n][k] (bf16), zero X pad rows.
// ---------------------------------------------------------------------------
__global__ void prep_kernel(const float* __restrict__ neigh_w,
                            const float* __restrict__ self_w,
                            const float* __restrict__ self_atten,
                            const float* __restrict__ neigh_atten,
                            const float* __restrict__ v,
                            float* __restrict__ u_self, float* __restrict__ u_neigh,
                            unsigned short* __restrict__ Wt,
                            unsigned short* __restrict__ X) {
    int idx = blockIdx.x * blockDim.x + threadIdx.x;
    int stride = gridDim.x * blockDim.x;

    // Wt[n][k] = (k < 512 ? self_w[k][n] : neigh_w[k-512][n]) as bf16
    // (strided reads, but the 2 MB source is L2-resident; ~2 us of L2 traffic)
    for (int i = idx; i < D_OUT * KTOT; i += stride) {
        int n = i >> 10;
        int k = i & (KTOT - 1);
        float w = (k < D_IN) ? self_w[k * D_OUT + n] : neigh_w[(k - D_IN) * D_OUT + n];
        Wt[i] = f2bf(w);
    }
    // u vectors (1024 dot products of length 64)
    for (int i = idx; i < 2 * D_IN; i += stride) {
        const float* row = (i < D_IN) ? (self_atten + (size_t)i * ATTEN_D)
                                      : (neigh_atten + (size_t)(i - D_IN) * ATTEN_D);
        float s = 0.f;
        #pragma unroll
        for (int j = 0; j < ATTEN_D; ++j) s = fmaf(row[j], v[j], s);
        if (i < D_IN) u_self[i] = s; else u_neigh[i - D_IN] = s;
    }
    // zero pad rows of X (rows N_NODES..M_PAD-1); ws is re-poisoned each call
    for (int i = idx; i < (M_PAD - N_NODES) * KTOT; i += stride) {
        X[(size_t)N_NODES * KTOT + i] = 0;
    }
}

// ---------------------------------------------------------------------------
// Kernel 1: wave-per-node aggregation. 256 threads = 4 independent waves,
// wave w handles node 4*blockIdx+w. NO LDS, NO __syncthreads — softmax sum,
// coef broadcast, and gate dots all via in-wave shuffles. Lane owns the 8
// consecutive floats [8*lane, 8*lane+7] of the 512-wide row, so each X half
// is written as a single 16 B store.
// ---------------------------------------------------------------------------
__global__ __launch_bounds__(256) void aggregate_kernel(
        const float* __restrict__ self_vecs, const float* __restrict__ neigh_vecs,
        const float* __restrict__ neigh_weight, const int* __restrict__ neigh_column,
        const float* __restrict__ alpha,
        const float* __restrict__ u_self, const float* __restrict__ u_neigh,
        unsigned short* __restrict__ X) {
    const int lane = threadIdx.x & 63;
    const int n = blockIdx.x * 4 + (threadIdx.x >> 6);   // N_NODES % 4 == 0

    // --- softmax coefficients (lanes 0..19 hold coef, rest hold 0) ---
    float e = 0.f, wgt = 0.f;
    if (lane < S_NB) {
        e = expf(alpha[neigh_column[n * S_NB + lane]]);
        wgt = neigh_weight[n * S_NB + lane];
    }
    float ssum = e;
    #pragma unroll
    for (int off = 32; off > 0; off >>= 1) ssum += __shfl_xor(ssum, off, 64);
    float coefv = wgt * e / ssum;

    // --- stream 20 neighbor rows, weighted accumulate ---
    const float4* nb = (const float4*)(neigh_vecs + (size_t)n * S_NB * D_IN);
    float4 acc0 = make_float4(0.f, 0.f, 0.f, 0.f);
    float4 acc1 = make_float4(0.f, 0.f, 0.f, 0.f);
    #pragma unroll
    for (int s = 0; s < S_NB; ++s) {
        float c = __shfl(coefv, s, 64);
        float4 x0 = nb[s * 128 + 2 * lane];
        float4 x1 = nb[s * 128 + 2 * lane + 1];
        acc0.x = fmaf(c, x0.x, acc0.x); acc0.y = fmaf(c, x0.y, acc0.y);
        acc0.z = fmaf(c, x0.z, acc0.z); acc0.w = fmaf(c, x0.w, acc0.w);
        acc1.x = fmaf(c, x1.x, acc1.x); acc1.y = fmaf(c, x1.y, acc1.y);
        acc1.z = fmaf(c, x1.z, acc1.z); acc1.w = fmaf(c, x1.w, acc1.w);
    }

    // --- gate dots (butterfly: every lane ends with the full sums) ---
    const float4* svp = (const float4*)(self_vecs + (size_t)n * D_IN);
    float4 sv0 = svp[2 * lane], sv1 = svp[2 * lane + 1];
    float4 us0 = ((const float4*)u_self)[2 * lane];
    float4 us1 = ((const float4*)u_self)[2 * lane + 1];
    float4 un0 = ((const float4*)u_neigh)[2 * lane];
    float4 un1 = ((const float4*)u_neigh)[2 * lane + 1];
    float p1 = sv0.x * us0.x + sv0.y * us0.y + sv0.z * us0.z + sv0.w * us0.w
             + sv1.x * us1.x + sv1.y * us1.y + sv1.z * us1.z + sv1.w * us1.w;
    float p2 = acc0.x * un0.x + acc0.y * un0.y + acc0.z * un0.z + acc0.w * un0.w
             + acc1.x * un1.x + acc1.y * un1.y + acc1.z * un1.z + acc1.w * un1.w;
    #pragma unroll
    for (int off = 32; off > 0; off >>= 1) {
        p1 += __shfl_xor(p1, off, 64);
        p2 += __shfl_xor(p2, off, 64);
    }
    float a_s = expf(tanhf(2.0f * p1));
    float a_n = expf(tanhf(p2 + p1));
    float inv = 1.0f / (a_s + a_n);
    float gs = a_s * inv, gn = a_n * inv;

    // --- write X row: [gs*self | gn*neigh_sum] as bf16, 16 B per store ---
    unsigned short* xrow = X + (size_t)n * KTOT;
    u16x8 o;
    o[0] = f2bf(gs * sv0.x); o[1] = f2bf(gs * sv0.y);
    o[2] = f2bf(gs * sv0.z); o[3] = f2bf(gs * sv0.w);
    o[4] = f2bf(gs * sv1.x); o[5] = f2bf(gs * sv1.y);
    o[6] = f2bf(gs * sv1.z); o[7] = f2bf(gs * sv1.w);
    *(u16x8*)(xrow + 8 * lane) = o;
    o[0] = f2bf(gn * acc0.x); o[1] = f2bf(gn * acc0.y);
    o[2] = f2bf(gn * acc0.z); o[3] = f2bf(gn * acc0.w);
    o[4] = f2bf(gn * acc1.x); o[5] = f2bf(gn * acc1.y);
    o[6] = f2bf(gn * acc1.z); o[7] = f2bf(gn * acc1.w);
    *(u16x8*)(xrow + D_IN + 8 * lane) = o;
}

// ---------------------------------------------------------------------------
// Kernel 2: out = relu(X[M,1024] @ W[1024,512]) using bf16 MFMA.
// BM=64, BN=128, BK=64; 256 threads = 4 waves in 2x2 grid; each wave 32x64.
// ---------------------------------------------------------------------------
#define BM 64
#define BN 128
#define BK 64

__global__ __launch_bounds__(256) void gemm_kernel(
        const unsigned short* __restrict__ X, const unsigned short* __restrict__ Wt,
        float* __restrict__ out) {
    __shared__ __align__(16) unsigned short As[BM * BK];   // [64][64]  8 KB
    __shared__ __align__(16) unsigned short Bs[BN * BK];   // [128][64] 16 KB, rows = out cols
    const int tid = threadIdx.x;
    const int lane = tid & 63;
    const int wid = tid >> 6;
    const int m0 = blockIdx.y * BM;
    const int n0 = blockIdx.x * BN;
    const int wm = (wid >> 1) * 32;
    const int wn = (wid & 1) * 64;
    const int quad = lane >> 4;
    const int mrow = lane & 15;

    f32x4 acc[2][4];
    f32x4 zero = {0.f, 0.f, 0.f, 0.f};
    #pragma unroll
    for (int i = 0; i < 2; ++i)
        #pragma unroll
        for (int j = 0; j < 4; ++j) acc[i][j] = zero;

    // staging: thread t loads 16B at row (chunk*32 + t/8), kpos (t%8)*8.
    // LDS dest = chunk_base + t*8 elements = wave-uniform base + lane*16B. OK.
    const int srow = tid >> 3;          // 0..31
    const int skp  = (tid & 7) * 8;     // bf16 k offset within BK
    const unsigned short* gA0 = X  + (size_t)(m0 + srow) * KTOT + skp;
    const unsigned short* gA1 = X  + (size_t)(m0 + 32 + srow) * KTOT + skp;
    const unsigned short* gB0 = Wt + (size_t)(n0 + srow) * KTOT + skp;
    const unsigned short* gB1 = Wt + (size_t)(n0 + 32 + srow) * KTOT + skp;
    const unsigned short* gB2 = Wt + (size_t)(n0 + 64 + srow) * KTOT + skp;
    const unsigned short* gB3 = Wt + (size_t)(n0 + 96 + srow) * KTOT + skp;
    unsigned short* lA0 = As + tid * 8;
    unsigned short* lA1 = As + 2048 + tid * 8;
    unsigned short* lB0 = Bs + tid * 8;
    unsigned short* lB1 = Bs + 2048 + tid * 8;
    unsigned short* lB2 = Bs + 4096 + tid * 8;
    unsigned short* lB3 = Bs + 6144 + tid * 8;

    for (int k0 = 0; k0 < KTOT; k0 += BK) {
        __syncthreads();               // LDS safe to overwrite
        gl_lds16(gA0 + k0, lA0);
        gl_lds16(gA1 + k0, lA1);
        gl_lds16(gB0 + k0, lB0);
        gl_lds16(gB1 + k0, lB1);
        gl_lds16(gB2 + k0, lB2);
        gl_lds16(gB3 + k0, lB3);
        __syncthreads();               // staged data visible

        #pragma unroll
        for (int s = 0; s < 2; ++s) {
            bf16x8 a[2], b[4];
            #pragma unroll
            for (int i = 0; i < 2; ++i)
                a[i] = *(const bf16x8*)(As + (wm + i * 16 + mrow) * BK + s * 32 + quad * 8);
            #pragma unroll
            for (int j = 0; j < 4; ++j)
                b[j] = *(const bf16x8*)(Bs + (wn + j * 16 + mrow) * BK + s * 32 + quad * 8);
            #pragma unroll
            for (int i = 0; i < 2; ++i)
                #pragma unroll
                for (int j = 0; j < 4; ++j)
                    acc[i][j] = __builtin_amdgcn_mfma_f32_16x16x32_bf16(a[i], b[j], acc[i][j], 0, 0, 0);
        }
    }

    // epilogue: C/D layout col=lane&15, row=quad*4+reg
    #pragma unroll
    for (int i = 0; i < 2; ++i) {
        int rbase = m0 + wm + i * 16 + quad * 4;
        #pragma unroll
        for (int j = 0; j < 4; ++j) {
            int c = n0 + wn + j * 16 + mrow;
            #pragma unroll
            for (int r = 0; r < 4; ++r) {
                int R = rbase + r;
                if (R < N_NODES)
                    out[(size_t)R * D_OUT + c] = fmaxf(acc[i][j][r], 0.f);
            }
        }
    }
}

extern "C" void kernel_launch(void* const* d_in, const int* in_sizes, int n_in,
                              void* d_out, int out_size, void* d_ws, size_t ws_size,
                              hipStream_t stream) {
    const float* self_vecs     = (const float*)d_in[0];
    const float* neigh_vecs    = (const float*)d_in[1];
    const float* neigh_weight  = (const float*)d_in[2];
    const int*   neigh_column  = (const int*)d_in[3];
    const float* neigh_weights = (const float*)d_in[4];
    const float* self_weights  = (const float*)d_in[5];
    const float* alpha         = (const float*)d_in[6];
    const float* self_atten    = (const float*)d_in[7];
    const float* neigh_atten   = (const float*)d_in[8];
    const float* v             = (const float*)d_in[9];
    float* out = (float*)d_out;

    char* ws = (char*)d_ws;
    float* u_self  = (float*)ws;                                   // 512 f32
    float* u_neigh = u_self + D_IN;                                // 512 f32
    unsigned short* Wt = (unsigned short*)(ws + 4096);             // 512*1024 bf16 = 1 MB
    unsigned short* X  = (unsigned short*)(ws + 4096 + (size_t)D_OUT * KTOT * 2); // M_PAD*1024 bf16

    hipLaunchKernelGGL(prep_kernel, dim3(1024), dim3(256), 0, stream,
                       neigh_weights, self_weights, self_atten, neigh_atten, v,
                       u_self, u_neigh, Wt, X);
    hipLaunchKernelGGL(aggregate_kernel, dim3(N_NODES / 4), dim3(256), 0, stream,
                       self_vecs, neigh_vecs, neigh_weight, neigh_column, alpha,
                       u_self, u_neigh, X);
    hipLaunchKernelGGL(gemm_kernel, dim3(D_OUT / BN, M_PAD / BM), dim3(256), 0, stream,
                       X, Wt, out);
}